// Round 1
// 1018.786 us; speedup vs baseline: 1.0289x; 1.0289x over previous
//
#include <hip/hip_runtime.h>
#include <cstddef>

static constexpr int B_ = 8;
static constexpr int H_ = 256;
static constexpr int W_ = 256;
static constexpr int HW_ = H_ * W_;
static constexpr int NPIX = B_ * HW_;

typedef __attribute__((ext_vector_type(8))) short short8;
typedef __attribute__((ext_vector_type(4))) float f32x4;

__device__ __forceinline__ float bf2f(short s) {
  union { unsigned u; float f; } c;
  c.u = ((unsigned)(unsigned short)s) << 16;
  return c.f;
}
__device__ __forceinline__ short f2bf(float f) {
  union { float f; unsigned u; } c; c.f = f;
  unsigned u = c.u;
  unsigned r = u + 0x7FFFu + ((u >> 16) & 1u);   // RNE
  return (short)(r >> 16);
}

// ---------------------------------------------------------------------------
// Mask kernel: cnt = clamp(cin * boxsum3x3_dil(m), 1e-5), mnew = maxpool3x3_dil
// ---------------------------------------------------------------------------
__global__ void mask_kernel(const float* __restrict__ m, float* __restrict__ cnt,
                            float* __restrict__ mnew, int d, float cin) {
  int idx = blockIdx.x * 256 + threadIdx.x;
  int b = idx >> 16;
  int hw = idx & (HW_ - 1);
  int h = hw >> 8, w = hw & (W_ - 1);
  const float* mb = m + b * HW_;
  float s = 0.f, mx = 0.f;
#pragma unroll
  for (int kh = 0; kh < 3; ++kh) {
    int hh = h + (kh - 1) * d;
    if ((unsigned)hh >= (unsigned)H_) continue;
#pragma unroll
    for (int kw = 0; kw < 3; ++kw) {
      int ww = w + (kw - 1) * d;
      if ((unsigned)ww >= (unsigned)W_) continue;
      float v = mb[hh * W_ + ww];
      s += v;
      mx = fmaxf(mx, v);
    }
  }
  cnt[idx] = fmaxf(s * cin, 1e-5f);
  mnew[idx] = mx;
}

// ---------------------------------------------------------------------------
// Weight prepack into MFMA B-fragment order, bf16.
// k-space: k = t*CINP + ci (3x3) or k = ci (1x1), K padded to S*32.
// Fragment element (s, nb, lane, j) <- k = s*32 + (lane>>4)*8 + j,
// n = nb*16 + (lane&15). Zeros for k >= 9*CINP or ci >= CINR.
// ---------------------------------------------------------------------------
__global__ void pack_w(const float* __restrict__ Wsrc, short* __restrict__ pk,
                       int CINP, int CINR, int COUT, int S, int is1x1) {
  int idx = blockIdx.x * 256 + threadIdx.x;
  int NB = COUT >> 4;
  if (idx >= S * NB * 512) return;
  int j = idx & 7;
  int lane = (idx >> 3) & 63;
  int nb = (idx >> 9) % NB;
  int s = idx / (NB << 9);
  int k = s * 32 + ((lane >> 4) << 3) + j;
  int n = (nb << 4) + (lane & 15);
  float v = 0.f;
  if (is1x1) {
    if (k < CINR) v = Wsrc[n * CINR + k];
  } else if (k < 9 * CINP) {
    int t = k / CINP, ci = k % CINP;
    if (ci < CINR) v = Wsrc[(n * CINR + ci) * 9 + t];
  }
  pk[idx] = f2bf(v);
}

// ---------------------------------------------------------------------------
// prep0: feat NCHW fp32 * mask -> NHWC bf16 (32 channels)
// ---------------------------------------------------------------------------
__global__ void prep0(const float* __restrict__ feat, const float* __restrict__ m,
                      short* __restrict__ xm) {
  int pix = blockIdx.x * 256 + threadIdx.x;
  float mv = m[pix];
  int b = pix >> 16, hw = pix & (HW_ - 1);
  const float* fp = feat + (size_t)b * 32 * HW_ + hw;
  short8 ov[4];
#pragma unroll
  for (int k = 0; k < 4; ++k)
#pragma unroll
    for (int c = 0; c < 8; ++c)
      ov[k][c] = f2bf(fp[(size_t)(k * 8 + c) * HW_] * mv);
  short8* dst = (short8*)(xm + (size_t)pix * 32);
#pragma unroll
  for (int k = 0; k < 4; ++k) dst[k] = ov[k];
}

// ---------------------------------------------------------------------------
// BN stats over NHWC bf16 y (C = 8<<c8sh channels): per-channel sum/sumsq.
// ---------------------------------------------------------------------------
__global__ void stats_k(const short* __restrict__ y, float* __restrict__ st, int c8sh) {
  int C8 = 1 << c8sh;
  int g = blockIdx.x * 256 + threadIdx.x;
  int chunk = g & (C8 - 1);
  int stride = (1024 * 256) >> c8sh;
  float s[8] = {0, 0, 0, 0, 0, 0, 0, 0}, q[8] = {0, 0, 0, 0, 0, 0, 0, 0};
  for (int p = g >> c8sh; p < NPIX; p += stride) {
    short8 v = *(const short8*)(y + (((size_t)p << c8sh) + chunk) * 8);
#pragma unroll
    for (int c = 0; c < 8; ++c) { float f = bf2f(v[c]); s[c] += f; q[c] += f * f; }
  }
  __shared__ float bins[256];
  int C = C8 * 8;
  for (int i = threadIdx.x; i < 2 * C; i += 256) bins[i] = 0.f;
  __syncthreads();
#pragma unroll
  for (int c = 0; c < 8; ++c) {
    atomicAdd(&bins[2 * (chunk * 8 + c)], s[c]);
    atomicAdd(&bins[2 * (chunk * 8 + c) + 1], q[c]);
  }
  __syncthreads();
  for (int i = threadIdx.x; i < 2 * C; i += 256) atomicAdd(&st[i], bins[i]);
}

__global__ void bn_prep(float* __restrict__ st, const float* __restrict__ g,
                        const float* __restrict__ be, int C, float invN) {
  int c = threadIdx.x;
  if (c >= C) return;
  float mean = st[2 * c] * invN;
  float var = st[2 * c + 1] * invN - mean * mean;
  float a = g[c] * rsqrtf(var + 1e-5f);
  st[2 * c] = a;
  st[2 * c + 1] = be[c] - a * mean;
}

// ---------------------------------------------------------------------------
// prep_bn: y bf16 NHWC (8<<cish ch) -> BN+LeakyReLU (+mask mult) -> bf16 NHWC
// (8<<cosh ch), zero-padding channels >= 8<<cish.
// ---------------------------------------------------------------------------
__global__ void prep_bn(const short* __restrict__ y, const float* __restrict__ st,
                        const float* __restrict__ m, short* __restrict__ xo,
                        int cish, int cosh) {
  int idx = blockIdx.x * 256 + threadIdx.x;
  int chunk = idx & ((1 << cosh) - 1);
  int pix = idx >> cosh;
  short8 ov = {0, 0, 0, 0, 0, 0, 0, 0};
  if (chunk < (1 << cish)) {
    float mv = m ? m[pix] : 1.f;
    short8 yv = *(const short8*)(y + (((size_t)pix << cish) + chunk) * 8);
#pragma unroll
    for (int c = 0; c < 8; ++c) {
      int cf = chunk * 8 + c;
      float v = fmaf(st[2 * cf], bf2f(yv[c]), st[2 * cf + 1]);
      v = v >= 0.f ? v : 0.01f * v;
      ov[c] = f2bf(v * mv);
    }
  }
  *(short8*)(xo + (size_t)idx * 8) = ov;
}

// ---------------------------------------------------------------------------
// MFMA implicit-GEMM 3x3 dilated conv. NHWC bf16 in/out, no LDS.
// Wave tile: MF*16 pixels x NF*16 cout. All pointers built from clamped
// coordinates (always in-bounds); zpad selected for invalid taps.
// ---------------------------------------------------------------------------
template <int CIN, int COUT, int D, int MF, int NF, int NSPLIT>
__global__ __launch_bounds__(256) void conv3_mfma(
    const short* __restrict__ xm, const short* __restrict__ pk,
    const float* __restrict__ cnt, const float* __restrict__ bias,
    short* __restrict__ y, const short* __restrict__ zpad) {
  constexpr int BM = MF * 16 * (4 / NSPLIT);
  constexpr int NB = COUT / 16;
  constexpr int CC = CIN / 32;

  int lane = threadIdx.x & 63;
  int wv = threadIdx.x >> 6;
  int quad = lane >> 4, l16 = lane & 15;
  int w0 = blockIdx.x * BM;
  int h = blockIdx.y;
  int b = blockIdx.z;
  int nsec = wv % NSPLIT;
  int msec = wv / NSPLIT;
  int mw0 = w0 + msec * MF * 16;
  int nb0 = nsec * NF;

  f32x4 acc[MF][NF];
#pragma unroll
  for (int i = 0; i < MF; ++i)
#pragma unroll
    for (int j = 0; j < NF; ++j) acc[i][j] = (f32x4){0.f, 0.f, 0.f, 0.f};

  const short* pkw = pk + (size_t)(nb0 * 64 + lane) * 8;
  const short* zp8 = zpad + quad * 8;

#pragma unroll
  for (int t = 0; t < 9; ++t) {
    int hh = h + (t / 3 - 1) * D;
    int dw = (t % 3 - 1) * D;
    bool hok = (unsigned)hh < (unsigned)H_;
    int hcl = hok ? hh : 0;                       // clamped: in-bounds always
    const short* rowp = xm + ((size_t)(b * H_ + hcl) * W_) * CIN + quad * 8;
    const short* ap[MF];
#pragma unroll
    for (int i = 0; i < MF; ++i) {
      int ww = mw0 + i * 16 + l16 + dw;
      bool v = hok && ((unsigned)ww < (unsigned)W_);
      int wcl = v ? ww : 0;                       // clamped: in-bounds always
      const short* pin = rowp + (size_t)wcl * CIN;
      ap[i] = v ? pin : zp8;
    }
#pragma unroll
    for (int cc = 0; cc < CC; ++cc) {
      int s = t * CC + cc;
      short8 a[MF], bb[NF];
#pragma unroll
      for (int i = 0; i < MF; ++i) a[i] = *(const short8*)(ap[i] + cc * 32);
#pragma unroll
      for (int j = 0; j < NF; ++j)
        bb[j] = *(const short8*)(pkw + ((size_t)s * NB + j) * 512);
#pragma unroll
      for (int i = 0; i < MF; ++i)
#pragma unroll
        for (int j = 0; j < NF; ++j)
          acc[i][j] = __builtin_amdgcn_mfma_f32_16x16x32_bf16(a[i], bb[j], acc[i][j], 0, 0, 0);
    }
  }

  // Epilogue: /cnt + bias, store NHWC bf16. D-frag: col(n)=lane&15, row(m)=quad*4+r.
  const size_t rowb = (size_t)(b * H_ + h) * W_;
#pragma unroll
  for (int i = 0; i < MF; ++i) {
#pragma unroll
    for (int r = 0; r < 4; ++r) {
      int pw = mw0 + i * 16 + quad * 4 + r;
      float ic = 1.f / cnt[(size_t)b * HW_ + h * W_ + pw];
#pragma unroll
      for (int j = 0; j < NF; ++j) {
        int co = (nb0 + j) * 16 + l16;
        float v = acc[i][j][r] * ic + bias[co];
        y[(rowb + pw) * COUT + co] = f2bf(v);
      }
    }
  }
}

// ---------------------------------------------------------------------------
// Final 1x1 conv: NHWC bf16 (128) -> NCHW fp32 d_out (64), + bias.
// ---------------------------------------------------------------------------
__global__ __launch_bounds__(256) void conv1x1_mfma(
    const short* __restrict__ xf, const short* __restrict__ pk,
    const float* __restrict__ bias, float* __restrict__ out) {
  constexpr int CIN = 128, NB = 4;
  int lane = threadIdx.x & 63, wv = threadIdx.x >> 6;
  int quad = lane >> 4, l16 = lane & 15;
  int w0 = blockIdx.x * 128, h = blockIdx.y, b = blockIdx.z;
  int mw0 = w0 + wv * 32;
  f32x4 acc[2][4];
#pragma unroll
  for (int i = 0; i < 2; ++i)
#pragma unroll
    for (int j = 0; j < 4; ++j) acc[i][j] = (f32x4){0.f, 0.f, 0.f, 0.f};
  const short* base0 = xf + ((size_t)(b * H_ + h) * W_ + mw0 + l16) * CIN + quad * 8;
  const short* pkw = pk + (size_t)lane * 8;
#pragma unroll
  for (int s = 0; s < 4; ++s) {
    short8 a0 = *(const short8*)(base0 + s * 32);
    short8 a1 = *(const short8*)(base0 + 16 * CIN + s * 32);
    short8 bb[4];
#pragma unroll
    for (int j = 0; j < 4; ++j) bb[j] = *(const short8*)(pkw + ((size_t)s * NB + j) * 512);
#pragma unroll
    for (int j = 0; j < 4; ++j) {
      acc[0][j] = __builtin_amdgcn_mfma_f32_16x16x32_bf16(a0, bb[j], acc[0][j], 0, 0, 0);
      acc[1][j] = __builtin_amdgcn_mfma_f32_16x16x32_bf16(a1, bb[j], acc[1][j], 0, 0, 0);
    }
  }
#pragma unroll
  for (int i = 0; i < 2; ++i)
#pragma unroll
    for (int r = 0; r < 4; ++r) {
      int pw = mw0 + i * 16 + quad * 4 + r;
#pragma unroll
      for (int j = 0; j < 4; ++j) {
        int co = j * 16 + l16;
        out[((size_t)b * 64 + co) * HW_ + h * W_ + pw] = acc[i][j][r] + bias[co];
      }
    }
}

__global__ void copy4_kernel(const float4* __restrict__ src, float4* __restrict__ dst) {
  int idx = blockIdx.x * 256 + threadIdx.x;
  dst[idx] = src[idx];
}

// ---------------------------------------------------------------------------
extern "C" void kernel_launch(void* const* d_in, const int* in_sizes, int n_in,
                              void* d_out, int out_size, void* d_ws, size_t ws_size,
                              hipStream_t stream) {
  const float* feat = (const float*)d_in[0];
  const float* mask = (const float*)d_in[1];
  const float *Wl[5], *bl[5], *gl[5], *bel[5];
  for (int l = 0; l < 5; ++l) {
    Wl[l]  = (const float*)d_in[2 + 4 * l];
    bl[l]  = (const float*)d_in[3 + 4 * l];
    gl[l]  = (const float*)d_in[4 + 4 * l];
    bel[l] = (const float*)d_in[5 + 4 * l];
  }
  const float* Wf = (const float*)d_in[22];
  const float* bf = (const float*)d_in[23];

  static const int COUTS[5] = {16, 32, 64, 64, 128};
  static const int CINP[5]  = {32, 32, 32, 64, 64};   // padded GEMM cin
  static const int CINR[5]  = {32, 16, 32, 64, 64};   // real weight cin
  static const int DILS[5]  = {1, 2, 1, 2, 1};
  static const int SST[5]   = {9, 9, 9, 18, 18};      // K-steps = 9*CINP/32
  static const int C8I[5]   = {1, 2, 3, 3, 4};        // Y chunks shift (cout/8)
  static const int C8O[5]   = {2, 2, 3, 3, 4};        // X chunks shift (next cin/8)

  // Workspace layout
  short* X = (short*)d_ws;                         // NPIX*128 bf16 (NHWC)
  short* Y = X + (size_t)NPIX * 128;               // NPIX*128 bf16 (NHWC)
  float* mA = (float*)(Y + (size_t)NPIX * 128);
  float* mB = mA + NPIX;
  float* cb = mB + NPIX;
  float* st = cb + NPIX;                           // 256 floats
  short* zp = (short*)(st + 256);                  // 512 shorts zero pad
  short* pkL[6];
  {
    short* p = zp + 512;
    for (int l = 0; l < 5; ++l) { pkL[l] = p; p += SST[l] * (COUTS[l] >> 4) * 512; }
    pkL[5] = p;                                    // 1x1: 4*4*512
  }

  hipMemsetAsync(zp, 0, 512 * sizeof(short), stream);
  for (int l = 0; l < 5; ++l) {
    int sz = SST[l] * (COUTS[l] >> 4) * 512;
    pack_w<<<sz / 256, 256, 0, stream>>>(Wl[l], pkL[l], CINP[l], CINR[l], COUTS[l], SST[l], 0);
  }
  pack_w<<<4 * 4 * 512 / 256, 256, 0, stream>>>(Wf, pkL[5], 128, 128, 64, 4, 1);

  prep0<<<NPIX / 256, 256, 0, stream>>>(feat, mask, X);

  const float* mcur = mask;

  for (int l = 0; l < 5; ++l) {
    int cout = COUTS[l];
    float* mnext = (l & 1) ? mB : mA;
    mask_kernel<<<NPIX / 256, 256, 0, stream>>>(mcur, cb, mnext, DILS[l], (float)CINR[l]);

    switch (l) {
      case 0: conv3_mfma<32, 16, 1, 4, 1, 1><<<dim3(1, 256, 8), 256, 0, stream>>>(X, pkL[0], cb, bl[0], Y, zp); break;
      case 1: conv3_mfma<32, 32, 2, 4, 2, 1><<<dim3(1, 256, 8), 256, 0, stream>>>(X, pkL[1], cb, bl[1], Y, zp); break;
      case 2: conv3_mfma<32, 64, 1, 4, 4, 1><<<dim3(1, 256, 8), 256, 0, stream>>>(X, pkL[2], cb, bl[2], Y, zp); break;
      case 3: conv3_mfma<64, 64, 2, 4, 4, 1><<<dim3(1, 256, 8), 256, 0, stream>>>(X, pkL[3], cb, bl[3], Y, zp); break;
      case 4: conv3_mfma<64, 128, 1, 4, 4, 2><<<dim3(2, 256, 8), 256, 0, stream>>>(X, pkL[4], cb, bl[4], Y, zp); break;
    }

    hipMemsetAsync(st, 0, 2 * cout * sizeof(float), stream);
    stats_k<<<1024, 256, 0, stream>>>(Y, st, C8I[l]);
    bn_prep<<<1, 128, 0, stream>>>(st, gl[l], bel[l], cout, 1.f / (float)NPIX);

    int c8o = 1 << C8O[l];
    prep_bn<<<(unsigned)((size_t)NPIX * c8o / 256), 256, 0, stream>>>(
        Y, st, l < 4 ? mnext : nullptr, X, C8I[l], C8O[l]);

    mcur = mnext;
  }

  conv1x1_mfma<<<dim3(2, 256, 8), 256, 0, stream>>>(X, pkL[5], bf, (float*)d_out);
  copy4_kernel<<<NPIX / 4 / 256, 256, 0, stream>>>(
      (const float4*)mcur, (float4*)d_out + ((size_t)B_ * 64 * HW_) / 4);
}

// Round 2
// 861.727 us; speedup vs baseline: 1.2164x; 1.1823x over previous
//
#include <hip/hip_runtime.h>
#include <cstddef>

static constexpr int B_ = 8;
static constexpr int H_ = 256;
static constexpr int W_ = 256;
static constexpr int HW_ = H_ * W_;
static constexpr int NPIX = B_ * HW_;

typedef __attribute__((ext_vector_type(8))) short short8;
typedef __attribute__((ext_vector_type(4))) float f32x4;

__device__ __forceinline__ float bf2f(short s) {
  union { unsigned u; float f; } c;
  c.u = ((unsigned)(unsigned short)s) << 16;
  return c.f;
}
__device__ __forceinline__ short f2bf(float f) {
  union { float f; unsigned u; } c; c.f = f;
  unsigned u = c.u;
  unsigned r = u + 0x7FFFu + ((u >> 16) & 1u);   // RNE
  return (short)(r >> 16);
}

// ---------------------------------------------------------------------------
// Mask kernel: cnt = clamp(cin * boxsum3x3_dil(m), 1e-5), mnew = maxpool3x3_dil
// ---------------------------------------------------------------------------
__global__ void mask_kernel(const float* __restrict__ m, float* __restrict__ cnt,
                            float* __restrict__ mnew, int d, float cin) {
  int idx = blockIdx.x * 256 + threadIdx.x;
  int b = idx >> 16;
  int hw = idx & (HW_ - 1);
  int h = hw >> 8, w = hw & (W_ - 1);
  const float* mb = m + b * HW_;
  float s = 0.f, mx = 0.f;
#pragma unroll
  for (int kh = 0; kh < 3; ++kh) {
    int hh = h + (kh - 1) * d;
    if ((unsigned)hh >= (unsigned)H_) continue;
#pragma unroll
    for (int kw = 0; kw < 3; ++kw) {
      int ww = w + (kw - 1) * d;
      if ((unsigned)ww >= (unsigned)W_) continue;
      float v = mb[hh * W_ + ww];
      s += v;
      mx = fmaxf(mx, v);
    }
  }
  cnt[idx] = fmaxf(s * cin, 1e-5f);
  mnew[idx] = mx;
}

// ---------------------------------------------------------------------------
// Weight prepack into MFMA B-fragment order, bf16.
// k-space: k = t*CINP + ci (3x3) or k = ci (1x1), K padded to S*32.
// Fragment element (s, nb, lane, j) <- k = s*32 + (lane>>4)*8 + j,
// n = nb*16 + (lane&15). Zeros for k >= 9*CINP or ci >= CINR.
// ---------------------------------------------------------------------------
__global__ void pack_w(const float* __restrict__ Wsrc, short* __restrict__ pk,
                       int CINP, int CINR, int COUT, int S, int is1x1) {
  int idx = blockIdx.x * 256 + threadIdx.x;
  int NB = COUT >> 4;
  if (idx >= S * NB * 512) return;
  int j = idx & 7;
  int lane = (idx >> 3) & 63;
  int nb = (idx >> 9) % NB;
  int s = idx / (NB << 9);
  int k = s * 32 + ((lane >> 4) << 3) + j;
  int n = (nb << 4) + (lane & 15);
  float v = 0.f;
  if (is1x1) {
    if (k < CINR) v = Wsrc[n * CINR + k];
  } else if (k < 9 * CINP) {
    int t = k / CINP, ci = k % CINP;
    if (ci < CINR) v = Wsrc[(n * CINR + ci) * 9 + t];
  }
  pk[idx] = f2bf(v);
}

// ---------------------------------------------------------------------------
// prep0: feat NCHW fp32 * mask -> NHWC bf16 (32 channels)
// ---------------------------------------------------------------------------
__global__ void prep0(const float* __restrict__ feat, const float* __restrict__ m,
                      short* __restrict__ xm) {
  int pix = blockIdx.x * 256 + threadIdx.x;
  float mv = m[pix];
  int b = pix >> 16, hw = pix & (HW_ - 1);
  const float* fp = feat + (size_t)b * 32 * HW_ + hw;
  short8 ov[4];
#pragma unroll
  for (int k = 0; k < 4; ++k)
#pragma unroll
    for (int c = 0; c < 8; ++c)
      ov[k][c] = f2bf(fp[(size_t)(k * 8 + c) * HW_] * mv);
  short8* dst = (short8*)(xm + (size_t)pix * 32);
#pragma unroll
  for (int k = 0; k < 4; ++k) dst[k] = ov[k];
}

// ---------------------------------------------------------------------------
// BN stats over NHWC bf16 y (C = 8<<c8sh channels): per-channel sum/sumsq.
// ---------------------------------------------------------------------------
__global__ void stats_k(const short* __restrict__ y, float* __restrict__ st, int c8sh) {
  int C8 = 1 << c8sh;
  int g = blockIdx.x * 256 + threadIdx.x;
  int chunk = g & (C8 - 1);
  int stride = (1024 * 256) >> c8sh;
  float s[8] = {0, 0, 0, 0, 0, 0, 0, 0}, q[8] = {0, 0, 0, 0, 0, 0, 0, 0};
  for (int p = g >> c8sh; p < NPIX; p += stride) {
    short8 v = *(const short8*)(y + (((size_t)p << c8sh) + chunk) * 8);
#pragma unroll
    for (int c = 0; c < 8; ++c) { float f = bf2f(v[c]); s[c] += f; q[c] += f * f; }
  }
  __shared__ float bins[256];
  int C = C8 * 8;
  for (int i = threadIdx.x; i < 2 * C; i += 256) bins[i] = 0.f;
  __syncthreads();
#pragma unroll
  for (int c = 0; c < 8; ++c) {
    atomicAdd(&bins[2 * (chunk * 8 + c)], s[c]);
    atomicAdd(&bins[2 * (chunk * 8 + c) + 1], q[c]);
  }
  __syncthreads();
  for (int i = threadIdx.x; i < 2 * C; i += 256) atomicAdd(&st[i], bins[i]);
}

__global__ void bn_prep(float* __restrict__ st, const float* __restrict__ g,
                        const float* __restrict__ be, int C, float invN) {
  int c = threadIdx.x;
  if (c >= C) return;
  float mean = st[2 * c] * invN;
  float var = st[2 * c + 1] * invN - mean * mean;
  float a = g[c] * rsqrtf(var + 1e-5f);
  st[2 * c] = a;
  st[2 * c + 1] = be[c] - a * mean;
}

// ---------------------------------------------------------------------------
// prep_bn: y bf16 NHWC (8<<cish ch) -> BN+LeakyReLU (+mask mult) -> bf16 NHWC
// (8<<cosh ch), zero-padding channels >= 8<<cish.
// ---------------------------------------------------------------------------
__global__ void prep_bn(const short* __restrict__ y, const float* __restrict__ st,
                        const float* __restrict__ m, short* __restrict__ xo,
                        int cish, int cosh) {
  int idx = blockIdx.x * 256 + threadIdx.x;
  int chunk = idx & ((1 << cosh) - 1);
  int pix = idx >> cosh;
  short8 ov = {0, 0, 0, 0, 0, 0, 0, 0};
  if (chunk < (1 << cish)) {
    float mv = m ? m[pix] : 1.f;
    short8 yv = *(const short8*)(y + (((size_t)pix << cish) + chunk) * 8);
#pragma unroll
    for (int c = 0; c < 8; ++c) {
      int cf = chunk * 8 + c;
      float v = fmaf(st[2 * cf], bf2f(yv[c]), st[2 * cf + 1]);
      v = v >= 0.f ? v : 0.01f * v;
      ov[c] = f2bf(v * mv);
    }
  }
  *(short8*)(xo + (size_t)idx * 8) = ov;
}

// ---------------------------------------------------------------------------
// LDS-staged MFMA implicit-GEMM 3x3 dilated conv. NHWC bf16 in/out.
// Block: 512 threads (8 waves), tile TH rows x TW px, full COUT.
// Stage A-tile (with D-halo, zero-filled OOB) into LDS chunk-major
// [kchunk][row][col] (conflict-optimal for ds_read_b128), then barrier-free
// 9-tap K-loop reading A from LDS and packed B from global (L1/L2-hit).
// Wave wv -> (msec = wv/NSPLIT, nsec = wv%NSPLIT); wave tile = MF*16 px
// (consecutive in row-major block space) x NF*16 cout.
// ---------------------------------------------------------------------------
template <int CIN, int COUT, int D, int MF, int NF, int NSPLIT, int TH, int TW>
__global__ __launch_bounds__(512, 4) void conv3_lds(
    const short* __restrict__ xm, const short* __restrict__ pk,
    const float* __restrict__ cnt, const float* __restrict__ bias,
    short* __restrict__ y) {
  constexpr int KC = CIN / 8;        // 16B chunks per pixel
  constexpr int CC = CIN / 32;       // K-steps per tap
  constexpr int NB = COUT / 16;
  constexpr int RT = TH + 2 * D;     // staged rows
  constexpr int WT = TW + 2 * D;     // staged cols
  constexpr int NCH = RT * WT;       // px per chunk plane
  constexpr int NELEM = NCH * KC;    // 16B elements staged
  static_assert(TH * TW == (8 / NSPLIT) * MF * 16, "wave tiling mismatch");
  static_assert(NELEM * 16 <= 64 * 1024, "LDS over 64KB");

  __shared__ short lds[NELEM * 8];

  int tid = threadIdx.x;
  int lane = tid & 63;
  int wv = tid >> 6;
  int quad = lane >> 4, l16 = lane & 15;
  int b = blockIdx.z;
  int h0 = blockIdx.y * TH;
  int w0 = blockIdx.x * TW;

  // ---- stage A tile (zeros outside image) ----
  const short* xb = xm + (size_t)b * HW_ * CIN;
  for (int e = tid; e < NELEM; e += 512) {
    int c = e % KC;
    int p = (e / KC) % WT;
    int r = e / (KC * WT);
    int gh = h0 + r - D, gw = w0 + p - D;
    short8 v = {0, 0, 0, 0, 0, 0, 0, 0};
    if ((unsigned)gh < (unsigned)H_ && (unsigned)gw < (unsigned)W_)
      v = *(const short8*)(xb + ((size_t)gh * W_ + gw) * CIN + c * 8);
    *(short8*)(lds + ((size_t)c * NCH + r * WT + p) * 8) = v;
  }
  __syncthreads();

  int nsec = wv % NSPLIT;
  int msec = wv / NSPLIT;
  int nb0 = nsec * NF;

  f32x4 acc[MF][NF];
#pragma unroll
  for (int i = 0; i < MF; ++i)
#pragma unroll
    for (int j = 0; j < NF; ++j) acc[i][j] = (f32x4){0.f, 0.f, 0.f, 0.f};

  const short* pkw = pk + (size_t)(nb0 * 64 + lane) * 8;

  // per-frag LDS base (in 16B units), at tap (0,0): row_i*WT + col_i + l16
  int fb[MF];
#pragma unroll
  for (int i = 0; i < MF; ++i) {
    int flat = (msec * MF + i) * 16;
    fb[i] = (flat / TW) * WT + (flat % TW) + l16;
  }

#pragma unroll
  for (int t = 0; t < 9; ++t) {
    int toff = (t / 3) * D * WT + (t % 3) * D;
#pragma unroll
    for (int cc = 0; cc < CC; ++cc) {
      int s = t * CC + cc;
      int cbase = (cc * 4 + quad) * NCH + toff;
      short8 a[MF], bb[NF];
#pragma unroll
      for (int i = 0; i < MF; ++i)
        a[i] = *(const short8*)(lds + (size_t)(cbase + fb[i]) * 8);
#pragma unroll
      for (int j = 0; j < NF; ++j)
        bb[j] = *(const short8*)(pkw + ((size_t)s * NB + j) * 512);
#pragma unroll
      for (int i = 0; i < MF; ++i)
#pragma unroll
        for (int j = 0; j < NF; ++j)
          acc[i][j] = __builtin_amdgcn_mfma_f32_16x16x32_bf16(a[i], bb[j], acc[i][j], 0, 0, 0);
    }
  }

  // ---- epilogue: /cnt + bias, NHWC bf16 store ----
#pragma unroll
  for (int i = 0; i < MF; ++i) {
    int flat = (msec * MF + i) * 16;
    int row_i = flat / TW, col_i = flat % TW;
    int hout = h0 + row_i;
    const size_t rowb = (size_t)(b * H_ + hout) * W_;
#pragma unroll
    for (int r = 0; r < 4; ++r) {
      int pw = w0 + col_i + quad * 4 + r;
      float ic = 1.f / cnt[(size_t)b * HW_ + hout * W_ + pw];
#pragma unroll
      for (int j = 0; j < NF; ++j) {
        int co = (nb0 + j) * 16 + l16;
        float v = acc[i][j][r] * ic + bias[co];
        y[(rowb + pw) * COUT + co] = f2bf(v);
      }
    }
  }
}

// ---------------------------------------------------------------------------
// Final 1x1 conv: NHWC bf16 (128) -> NCHW fp32 d_out (64), + bias.
// ---------------------------------------------------------------------------
__global__ __launch_bounds__(256) void conv1x1_mfma(
    const short* __restrict__ xf, const short* __restrict__ pk,
    const float* __restrict__ bias, float* __restrict__ out) {
  constexpr int CIN = 128, NB = 4;
  int lane = threadIdx.x & 63, wv = threadIdx.x >> 6;
  int quad = lane >> 4, l16 = lane & 15;
  int w0 = blockIdx.x * 128, h = blockIdx.y, b = blockIdx.z;
  int mw0 = w0 + wv * 32;
  f32x4 acc[2][4];
#pragma unroll
  for (int i = 0; i < 2; ++i)
#pragma unroll
    for (int j = 0; j < 4; ++j) acc[i][j] = (f32x4){0.f, 0.f, 0.f, 0.f};
  const short* base0 = xf + ((size_t)(b * H_ + h) * W_ + mw0 + l16) * CIN + quad * 8;
  const short* pkw = pk + (size_t)lane * 8;
#pragma unroll
  for (int s = 0; s < 4; ++s) {
    short8 a0 = *(const short8*)(base0 + s * 32);
    short8 a1 = *(const short8*)(base0 + 16 * CIN + s * 32);
    short8 bb[4];
#pragma unroll
    for (int j = 0; j < 4; ++j) bb[j] = *(const short8*)(pkw + ((size_t)s * NB + j) * 512);
#pragma unroll
    for (int j = 0; j < 4; ++j) {
      acc[0][j] = __builtin_amdgcn_mfma_f32_16x16x32_bf16(a0, bb[j], acc[0][j], 0, 0, 0);
      acc[1][j] = __builtin_amdgcn_mfma_f32_16x16x32_bf16(a1, bb[j], acc[1][j], 0, 0, 0);
    }
  }
#pragma unroll
  for (int i = 0; i < 2; ++i)
#pragma unroll
    for (int r = 0; r < 4; ++r) {
      int pw = mw0 + i * 16 + quad * 4 + r;
#pragma unroll
      for (int j = 0; j < 4; ++j) {
        int co = j * 16 + l16;
        out[((size_t)b * 64 + co) * HW_ + h * W_ + pw] = acc[i][j][r] + bias[co];
      }
    }
}

__global__ void copy4_kernel(const float4* __restrict__ src, float4* __restrict__ dst) {
  int idx = blockIdx.x * 256 + threadIdx.x;
  dst[idx] = src[idx];
}

// ---------------------------------------------------------------------------
extern "C" void kernel_launch(void* const* d_in, const int* in_sizes, int n_in,
                              void* d_out, int out_size, void* d_ws, size_t ws_size,
                              hipStream_t stream) {
  const float* feat = (const float*)d_in[0];
  const float* mask = (const float*)d_in[1];
  const float *Wl[5], *bl[5], *gl[5], *bel[5];
  for (int l = 0; l < 5; ++l) {
    Wl[l]  = (const float*)d_in[2 + 4 * l];
    bl[l]  = (const float*)d_in[3 + 4 * l];
    gl[l]  = (const float*)d_in[4 + 4 * l];
    bel[l] = (const float*)d_in[5 + 4 * l];
  }
  const float* Wf = (const float*)d_in[22];
  const float* bf = (const float*)d_in[23];

  static const int COUTS[5] = {16, 32, 64, 64, 128};
  static const int CINP[5]  = {32, 32, 32, 64, 64};   // padded GEMM cin
  static const int CINR[5]  = {32, 16, 32, 64, 64};   // real weight cin
  static const int DILS[5]  = {1, 2, 1, 2, 1};
  static const int SST[5]   = {9, 9, 9, 18, 18};      // K-steps = 9*CINP/32
  static const int C8I[5]   = {1, 2, 3, 3, 4};        // Y chunks shift (cout/8)
  static const int C8O[5]   = {2, 2, 3, 3, 4};        // X chunks shift (next cin/8)

  // Workspace layout
  short* X = (short*)d_ws;                         // NPIX*128 bf16 (NHWC)
  short* Y = X + (size_t)NPIX * 128;               // NPIX*128 bf16 (NHWC)
  float* mA = (float*)(Y + (size_t)NPIX * 128);
  float* mB = mA + NPIX;
  float* cb = mB + NPIX;
  float* st = cb + NPIX;                           // 256 floats
  short* pkL[6];
  {
    short* p = (short*)(st + 256);
    for (int l = 0; l < 5; ++l) { pkL[l] = p; p += SST[l] * (COUTS[l] >> 4) * 512; }
    pkL[5] = p;                                    // 1x1: 4*4*512
  }

  for (int l = 0; l < 5; ++l) {
    int sz = SST[l] * (COUTS[l] >> 4) * 512;
    pack_w<<<sz / 256, 256, 0, stream>>>(Wl[l], pkL[l], CINP[l], CINR[l], COUTS[l], SST[l], 0);
  }
  pack_w<<<4 * 4 * 512 / 256, 256, 0, stream>>>(Wf, pkL[5], 128, 128, 64, 4, 1);

  prep0<<<NPIX / 256, 256, 0, stream>>>(feat, mask, X);

  const float* mcur = mask;

  for (int l = 0; l < 5; ++l) {
    int cout = COUTS[l];
    float* mnext = (l & 1) ? mB : mA;
    mask_kernel<<<NPIX / 256, 256, 0, stream>>>(mcur, cb, mnext, DILS[l], (float)CINR[l]);

    switch (l) {
      case 0: conv3_lds<32, 16, 1, 4, 1, 1, 8, 64><<<dim3(4, 32, 8), 512, 0, stream>>>(X, pkL[0], cb, bl[0], Y); break;
      case 1: conv3_lds<32, 32, 2, 4, 2, 1, 8, 64><<<dim3(4, 32, 8), 512, 0, stream>>>(X, pkL[1], cb, bl[1], Y); break;
      case 2: conv3_lds<32, 64, 1, 4, 4, 1, 8, 64><<<dim3(4, 32, 8), 512, 0, stream>>>(X, pkL[2], cb, bl[2], Y); break;
      case 3: conv3_lds<64, 64, 2, 4, 2, 2, 8, 32><<<dim3(8, 32, 8), 512, 0, stream>>>(X, pkL[3], cb, bl[3], Y); break;
      case 4: conv3_lds<64, 128, 1, 4, 4, 2, 4, 64><<<dim3(4, 64, 8), 512, 0, stream>>>(X, pkL[4], cb, bl[4], Y); break;
    }

    hipMemsetAsync(st, 0, 2 * cout * sizeof(float), stream);
    stats_k<<<1024, 256, 0, stream>>>(Y, st, C8I[l]);
    bn_prep<<<1, 128, 0, stream>>>(st, gl[l], bel[l], cout, 1.f / (float)NPIX);

    int c8o = 1 << C8O[l];
    prep_bn<<<(unsigned)((size_t)NPIX * c8o / 256), 256, 0, stream>>>(
        Y, st, l < 4 ? mnext : nullptr, X, C8I[l], C8O[l]);

    mcur = mnext;
  }

  conv1x1_mfma<<<dim3(2, 256, 8), 256, 0, stream>>>(X, pkL[5], bf, (float*)d_out);
  copy4_kernel<<<NPIX / 4 / 256, 256, 0, stream>>>(
      (const float4*)mcur, (float4*)d_out + ((size_t)B_ * 64 * HW_) / 4);
}

// Round 3
// 666.341 us; speedup vs baseline: 1.5730x; 1.2932x over previous
//
#include <hip/hip_runtime.h>
#include <cstddef>

static constexpr int B_ = 8;
static constexpr int H_ = 256;
static constexpr int W_ = 256;
static constexpr int HW_ = H_ * W_;
static constexpr int NPIX = B_ * HW_;

typedef __attribute__((ext_vector_type(8))) short short8;
typedef __attribute__((ext_vector_type(4))) float f32x4;

__device__ __forceinline__ float bf2f(short s) {
  union { unsigned u; float f; } c;
  c.u = ((unsigned)(unsigned short)s) << 16;
  return c.f;
}
__device__ __forceinline__ short f2bf(float f) {
  union { float f; unsigned u; } c; c.f = f;
  unsigned u = c.u;
  unsigned r = u + 0x7FFFu + ((u >> 16) & 1u);   // RNE
  return (short)(r >> 16);
}

// Pad chunk-plane size (16B units) so that an 8-lane phase of the staging
// write (c fastest) and the fragment read hit all 32 banks exactly once.
// KC=8 -> NCHP % 8 == 1 ; KC=4 -> NCHP % 8 == 2.
constexpr int pad_nch(int nch, int kc) {
  int res = (kc == 8) ? 1 : 2;
  while (nch % 8 != res) ++nch;
  return nch;
}

// ---------------------------------------------------------------------------
// Mask kernel: cnt = clamp(cin * boxsum3x3_dil(m), 1e-5), mnew = maxpool3x3_dil
// ---------------------------------------------------------------------------
__global__ void mask_kernel(const float* __restrict__ m, float* __restrict__ cnt,
                            float* __restrict__ mnew, int d, float cin) {
  int idx = blockIdx.x * 256 + threadIdx.x;
  int b = idx >> 16;
  int hw = idx & (HW_ - 1);
  int h = hw >> 8, w = hw & (W_ - 1);
  const float* mb = m + b * HW_;
  float s = 0.f, mx = 0.f;
#pragma unroll
  for (int kh = 0; kh < 3; ++kh) {
    int hh = h + (kh - 1) * d;
    if ((unsigned)hh >= (unsigned)H_) continue;
#pragma unroll
    for (int kw = 0; kw < 3; ++kw) {
      int ww = w + (kw - 1) * d;
      if ((unsigned)ww >= (unsigned)W_) continue;
      float v = mb[hh * W_ + ww];
      s += v;
      mx = fmaxf(mx, v);
    }
  }
  cnt[idx] = fmaxf(s * cin, 1e-5f);
  mnew[idx] = mx;
}

// ---------------------------------------------------------------------------
// Weight prepack into MFMA B-fragment order, bf16.
// ---------------------------------------------------------------------------
__global__ void pack_w(const float* __restrict__ Wsrc, short* __restrict__ pk,
                       int CINP, int CINR, int COUT, int S, int is1x1) {
  int idx = blockIdx.x * 256 + threadIdx.x;
  int NB = COUT >> 4;
  if (idx >= S * NB * 512) return;
  int j = idx & 7;
  int lane = (idx >> 3) & 63;
  int nb = (idx >> 9) % NB;
  int s = idx / (NB << 9);
  int k = s * 32 + ((lane >> 4) << 3) + j;
  int n = (nb << 4) + (lane & 15);
  float v = 0.f;
  if (is1x1) {
    if (k < CINR) v = Wsrc[n * CINR + k];
  } else if (k < 9 * CINP) {
    int t = k / CINP, ci = k % CINP;
    if (ci < CINR) v = Wsrc[(n * CINR + ci) * 9 + t];
  }
  pk[idx] = f2bf(v);
}

// ---------------------------------------------------------------------------
// prep0: feat NCHW fp32 * mask -> NHWC bf16 (32 channels)
// ---------------------------------------------------------------------------
__global__ void prep0(const float* __restrict__ feat, const float* __restrict__ m,
                      short* __restrict__ xm) {
  int pix = blockIdx.x * 256 + threadIdx.x;
  float mv = m[pix];
  int b = pix >> 16, hw = pix & (HW_ - 1);
  const float* fp = feat + (size_t)b * 32 * HW_ + hw;
  short8 ov[4];
#pragma unroll
  for (int k = 0; k < 4; ++k)
#pragma unroll
    for (int c = 0; c < 8; ++c)
      ov[k][c] = f2bf(fp[(size_t)(k * 8 + c) * HW_] * mv);
  short8* dst = (short8*)(xm + (size_t)pix * 32);
#pragma unroll
  for (int k = 0; k < 4; ++k) dst[k] = ov[k];
}

__global__ void bn_prep(float* __restrict__ st, const float* __restrict__ g,
                        const float* __restrict__ be, int C, float invN) {
  int c = threadIdx.x;
  if (c >= C) return;
  float mean = st[2 * c] * invN;
  float var = st[2 * c + 1] * invN - mean * mean;
  float a = g[c] * rsqrtf(var + 1e-5f);
  st[2 * c] = a;
  st[2 * c + 1] = be[c] - a * mean;
}

// ---------------------------------------------------------------------------
// LDS-staged MFMA implicit-GEMM 3x3 dilated conv with fused input BN and
// fused output BN-stats. NHWC bf16 in/out.
// FUSE=1: input x = leaky(a*y+b) * mask applied during staging (a,b from stIn;
//         per-thread chunk class c = tid%KC is loop-invariant -> params in regs).
// Epilogue: v = acc/cnt + bias -> y bf16, and per-channel sum/sumsq reduced
// via LDS bins + one global float-atomic per channel per block into stOut.
// Bank-conflict-free LDS: plane size padded to NCHP (see pad_nch).
// ---------------------------------------------------------------------------
template <int CIN, int CINR, int COUT, int D, int MF, int NF, int NSPLIT,
          int TH, int TW, int FUSE>
__global__ __launch_bounds__(512, 4) void conv3_lds(
    const short* __restrict__ xin, const short* __restrict__ pk,
    const float* __restrict__ cnt, const float* __restrict__ bias,
    const float* __restrict__ stIn, const float* __restrict__ mask,
    float* __restrict__ stOut, short* __restrict__ y) {
  constexpr int KC = CIN / 8;          // staged 16B chunks per pixel (padded)
  constexpr int KCR = (CINR + 7) / 8;  // real chunks present in input
  constexpr int ICH = FUSE ? CINR : CIN;
  constexpr int CC = CIN / 32;
  constexpr int NB = COUT / 16;
  constexpr int RT = TH + 2 * D;
  constexpr int WT = TW + 2 * D;
  constexpr int NCH = RT * WT;
  constexpr int NCHP = pad_nch(NCH, KC);
  constexpr int NELEM = NCH * KC;
  static_assert(TH * TW == (8 / NSPLIT) * MF * 16, "wave tiling mismatch");
  static_assert(NCHP * KC * 16 <= 62 * 1024, "LDS over budget");

  __shared__ short lds[NCHP * KC * 8];
  __shared__ float bins[2 * COUT];

  int tid = threadIdx.x;
  int lane = tid & 63;
  int wv = tid >> 6;
  int quad = lane >> 4, l16 = lane & 15;
  int b = blockIdx.z;
  int h0 = blockIdx.y * TH;
  int w0 = blockIdx.x * TW;

  for (int i = tid; i < 2 * COUT; i += 512) bins[i] = 0.f;

  // ---- stage A tile (zeros outside image / beyond real channels) ----
  int cl = tid % KC;                    // chunk class, invariant across rounds
  float av[8], bv[8];
  if (FUSE) {
#pragma unroll
    for (int k = 0; k < 8; ++k) {
      av[k] = stIn[2 * (cl * 8 + k)];
      bv[k] = stIn[2 * (cl * 8 + k) + 1];
    }
  }
  const short* xb = xin + (size_t)b * HW_ * ICH;
  const float* mb = mask + (size_t)b * HW_;
  for (int e = tid; e < NELEM; e += 512) {
    int p = (e / KC) % WT;
    int r = e / (KC * WT);
    int gh = h0 + r - D, gw = w0 + p - D;
    short8 v = {0, 0, 0, 0, 0, 0, 0, 0};
    if ((unsigned)gh < (unsigned)H_ && (unsigned)gw < (unsigned)W_ && cl < KCR) {
      short8 raw = *(const short8*)(xb + ((size_t)gh * W_ + gw) * ICH + cl * 8);
      if (FUSE) {
        float mv = mb[gh * W_ + gw];
#pragma unroll
        for (int k = 0; k < 8; ++k) {
          float f = fmaf(av[k], bf2f(raw[k]), bv[k]);
          f = f >= 0.f ? f : 0.01f * f;
          v[k] = f2bf(f * mv);
        }
      } else {
        v = raw;
      }
    }
    *(short8*)(lds + ((size_t)cl * NCHP + r * WT + p) * 8) = v;
  }
  __syncthreads();

  int nsec = wv % NSPLIT;
  int msec = wv / NSPLIT;
  int nb0 = nsec * NF;

  f32x4 acc[MF][NF];
#pragma unroll
  for (int i = 0; i < MF; ++i)
#pragma unroll
    for (int j = 0; j < NF; ++j) acc[i][j] = (f32x4){0.f, 0.f, 0.f, 0.f};

  const short* pkw = pk + (size_t)(nb0 * 64 + lane) * 8;

  int fb[MF];
#pragma unroll
  for (int i = 0; i < MF; ++i) {
    int flat = (msec * MF + i) * 16;
    fb[i] = (flat / TW) * WT + (flat % TW) + l16;
  }

#pragma unroll
  for (int t = 0; t < 9; ++t) {
    int toff = (t / 3) * D * WT + (t % 3) * D;
#pragma unroll
    for (int cc = 0; cc < CC; ++cc) {
      int s = t * CC + cc;
      int cbase = (cc * 4 + quad) * NCHP + toff;
      short8 a[MF], bb[NF];
#pragma unroll
      for (int i = 0; i < MF; ++i)
        a[i] = *(const short8*)(lds + (size_t)(cbase + fb[i]) * 8);
#pragma unroll
      for (int j = 0; j < NF; ++j)
        bb[j] = *(const short8*)(pkw + ((size_t)s * NB + j) * 512);
#pragma unroll
      for (int i = 0; i < MF; ++i)
#pragma unroll
        for (int j = 0; j < NF; ++j)
          acc[i][j] = __builtin_amdgcn_mfma_f32_16x16x32_bf16(a[i], bb[j], acc[i][j], 0, 0, 0);
    }
  }

  // ---- epilogue: /cnt + bias, NHWC bf16 store, fp32 stats accumulate ----
  float sums[NF], sqs[NF];
#pragma unroll
  for (int j = 0; j < NF; ++j) { sums[j] = 0.f; sqs[j] = 0.f; }
#pragma unroll
  for (int i = 0; i < MF; ++i) {
    int flat = (msec * MF + i) * 16;
    int row_i = flat / TW, col_i = flat % TW;
    int hout = h0 + row_i;
    const size_t rowb = (size_t)(b * H_ + hout) * W_;
#pragma unroll
    for (int r = 0; r < 4; ++r) {
      int pw = w0 + col_i + quad * 4 + r;
      float ic = 1.f / cnt[(size_t)b * HW_ + hout * W_ + pw];
#pragma unroll
      for (int j = 0; j < NF; ++j) {
        int co = (nb0 + j) * 16 + l16;
        float v = acc[i][j][r] * ic + bias[co];
        sums[j] += v;
        sqs[j] += v * v;
        y[(rowb + pw) * COUT + co] = f2bf(v);
      }
    }
  }
#pragma unroll
  for (int j = 0; j < NF; ++j) {
    int co = (nb0 + j) * 16 + l16;
    atomicAdd(&bins[2 * co], sums[j]);
    atomicAdd(&bins[2 * co + 1], sqs[j]);
  }
  __syncthreads();
  for (int i = tid; i < 2 * COUT; i += 512) atomicAdd(&stOut[i], bins[i]);
}

// ---------------------------------------------------------------------------
// Final 1x1 conv with fused input BN+leaky: NHWC bf16 (128) -> NCHW fp32 (64).
// ---------------------------------------------------------------------------
__global__ __launch_bounds__(256) void conv1x1_mfma(
    const short* __restrict__ xf, const short* __restrict__ pk,
    const float* __restrict__ stIn, const float* __restrict__ bias,
    float* __restrict__ out) {
  constexpr int CIN = 128, NB = 4;
  int lane = threadIdx.x & 63, wv = threadIdx.x >> 6;
  int quad = lane >> 4, l16 = lane & 15;
  int w0 = blockIdx.x * 128, h = blockIdx.y, b = blockIdx.z;
  int mw0 = w0 + wv * 32;
  f32x4 acc[2][4];
#pragma unroll
  for (int i = 0; i < 2; ++i)
#pragma unroll
    for (int j = 0; j < 4; ++j) acc[i][j] = (f32x4){0.f, 0.f, 0.f, 0.f};
  const short* base0 = xf + ((size_t)(b * H_ + h) * W_ + mw0 + l16) * CIN + quad * 8;
  const short* pkw = pk + (size_t)lane * 8;
#pragma unroll
  for (int s = 0; s < 4; ++s) {
    float aa[8], bb2[8];
#pragma unroll
    for (int k = 0; k < 8; ++k) {
      int ch = s * 32 + quad * 8 + k;
      aa[k] = stIn[2 * ch];
      bb2[k] = stIn[2 * ch + 1];
    }
    short8 r0 = *(const short8*)(base0 + s * 32);
    short8 r1 = *(const short8*)(base0 + 16 * CIN + s * 32);
    short8 a0, a1;
#pragma unroll
    for (int k = 0; k < 8; ++k) {
      float f0 = fmaf(aa[k], bf2f(r0[k]), bb2[k]);
      float f1 = fmaf(aa[k], bf2f(r1[k]), bb2[k]);
      a0[k] = f2bf(f0 >= 0.f ? f0 : 0.01f * f0);
      a1[k] = f2bf(f1 >= 0.f ? f1 : 0.01f * f1);
    }
    short8 bb[4];
#pragma unroll
    for (int j = 0; j < 4; ++j) bb[j] = *(const short8*)(pkw + ((size_t)s * NB + j) * 512);
#pragma unroll
    for (int j = 0; j < 4; ++j) {
      acc[0][j] = __builtin_amdgcn_mfma_f32_16x16x32_bf16(a0, bb[j], acc[0][j], 0, 0, 0);
      acc[1][j] = __builtin_amdgcn_mfma_f32_16x16x32_bf16(a1, bb[j], acc[1][j], 0, 0, 0);
    }
  }
#pragma unroll
  for (int i = 0; i < 2; ++i)
#pragma unroll
    for (int r = 0; r < 4; ++r) {
      int pw = mw0 + i * 16 + quad * 4 + r;
#pragma unroll
      for (int j = 0; j < 4; ++j) {
        int co = j * 16 + l16;
        out[((size_t)b * 64 + co) * HW_ + h * W_ + pw] = acc[i][j][r] + bias[co];
      }
    }
}

__global__ void copy4_kernel(const float4* __restrict__ src, float4* __restrict__ dst) {
  int idx = blockIdx.x * 256 + threadIdx.x;
  dst[idx] = src[idx];
}

// ---------------------------------------------------------------------------
extern "C" void kernel_launch(void* const* d_in, const int* in_sizes, int n_in,
                              void* d_out, int out_size, void* d_ws, size_t ws_size,
                              hipStream_t stream) {
  const float* feat = (const float*)d_in[0];
  const float* mask = (const float*)d_in[1];
  const float *Wl[5], *bl[5], *gl[5], *bel[5];
  for (int l = 0; l < 5; ++l) {
    Wl[l]  = (const float*)d_in[2 + 4 * l];
    bl[l]  = (const float*)d_in[3 + 4 * l];
    gl[l]  = (const float*)d_in[4 + 4 * l];
    bel[l] = (const float*)d_in[5 + 4 * l];
  }
  const float* Wf = (const float*)d_in[22];
  const float* bf = (const float*)d_in[23];

  static const int COUTS[5] = {16, 32, 64, 64, 128};
  static const int CINP[5]  = {32, 32, 32, 64, 64};   // padded GEMM cin
  static const int CINR[5]  = {32, 16, 32, 64, 64};   // real weight cin
  static const int SST[5]   = {9, 9, 9, 18, 18};      // K-steps = 9*CINP/32

  // Workspace layout: two ping-pong NHWC activation buffers + masks + st + packs
  short* Ya = (short*)d_ws;                        // NPIX*128 bf16
  short* Yb = Ya + (size_t)NPIX * 128;             // NPIX*128 bf16
  float* mA = (float*)(Yb + (size_t)NPIX * 128);
  float* mB = mA + NPIX;
  float* cb = mB + NPIX;
  float* st = cb + NPIX;                           // 5 * 256 floats
  short* pkL[6];
  {
    short* p = (short*)(st + 5 * 256);
    for (int l = 0; l < 5; ++l) { pkL[l] = p; p += SST[l] * (COUTS[l] >> 4) * 512; }
    pkL[5] = p;                                    // 1x1: 4*4*512
  }

  hipMemsetAsync(st, 0, 5 * 256 * sizeof(float), stream);
  for (int l = 0; l < 5; ++l) {
    int sz = SST[l] * (COUTS[l] >> 4) * 512;
    pack_w<<<sz / 256, 256, 0, stream>>>(Wl[l], pkL[l], CINP[l], CINR[l], COUTS[l], SST[l], 0);
  }
  pack_w<<<4 * 4 * 512 / 256, 256, 0, stream>>>(Wf, pkL[5], 128, 128, 64, 4, 1);

  prep0<<<NPIX / 256, 256, 0, stream>>>(feat, mask, Ya);

  const float* mcur = mask;
  // buffers ping-pong: conv l reads bufs[l&1], writes bufs[(l+1)&1]
  short* bufs[2] = {Ya, Yb};

  for (int l = 0; l < 5; ++l) {
    float* mnext = (l & 1) ? mB : mA;
    mask_kernel<<<NPIX / 256, 256, 0, stream>>>(mcur, cb, mnext, (l == 1 || l == 3) ? 2 : 1,
                                                (float)CINR[l]);
    const short* xin = bufs[l & 1];
    short* yout = bufs[(l + 1) & 1];
    const float* stP = (l > 0) ? st + (l - 1) * 256 : st;  // unused for l==0
    float* stO = st + l * 256;

    switch (l) {
      case 0: conv3_lds<32, 32, 16, 1, 4, 1, 1, 8, 64, 0>
                <<<dim3(4, 32, 8), 512, 0, stream>>>(xin, pkL[0], cb, bl[0], stP, mcur, stO, yout); break;
      case 1: conv3_lds<32, 16, 32, 2, 4, 2, 1, 8, 64, 1>
                <<<dim3(4, 32, 8), 512, 0, stream>>>(xin, pkL[1], cb, bl[1], stP, mcur, stO, yout); break;
      case 2: conv3_lds<32, 32, 64, 1, 4, 4, 1, 8, 64, 1>
                <<<dim3(4, 32, 8), 512, 0, stream>>>(xin, pkL[2], cb, bl[2], stP, mcur, stO, yout); break;
      case 3: conv3_lds<64, 64, 64, 2, 4, 2, 2, 8, 32, 1>
                <<<dim3(8, 32, 8), 512, 0, stream>>>(xin, pkL[3], cb, bl[3], stP, mcur, stO, yout); break;
      case 4: conv3_lds<64, 64, 128, 1, 4, 4, 2, 4, 64, 1>
                <<<dim3(4, 64, 8), 512, 0, stream>>>(xin, pkL[4], cb, bl[4], stP, mcur, stO, yout); break;
    }

    bn_prep<<<1, 128, 0, stream>>>(stO, gl[l], bel[l], COUTS[l], 1.f / (float)NPIX);
    mcur = mnext;
  }

  conv1x1_mfma<<<dim3(2, 256, 8), 256, 0, stream>>>(bufs[1], pkL[5], st + 4 * 256, bf,
                                                    (float*)d_out);
  copy4_kernel<<<NPIX / 4 / 256, 256, 0, stream>>>(
      (const float4*)mcur, (float4*)d_out + ((size_t)B_ * 64 * HW_) / 4);
}

// Round 4
// 619.500 us; speedup vs baseline: 1.6920x; 1.0756x over previous
//
#include <hip/hip_runtime.h>
#include <cstddef>

static constexpr int B_ = 8;
static constexpr int H_ = 256;
static constexpr int W_ = 256;
static constexpr int HW_ = H_ * W_;
static constexpr int NPIX = B_ * HW_;

typedef __attribute__((ext_vector_type(8))) short short8;
typedef __attribute__((ext_vector_type(4))) float f32x4;

__device__ __forceinline__ float bf2f(short s) {
  union { unsigned u; float f; } c;
  c.u = ((unsigned)(unsigned short)s) << 16;
  return c.f;
}
__device__ __forceinline__ short f2bf(float f) {
  union { float f; unsigned u; } c; c.f = f;
  unsigned u = c.u;
  unsigned r = u + 0x7FFFu + ((u >> 16) & 1u);   // RNE
  return (short)(r >> 16);
}
// HW packed f32->bf16 RNE (2 values / instr)
__device__ __forceinline__ unsigned cvt_pk_bf16(float lo, float hi) {
  unsigned r;
  asm("v_cvt_pk_bf16_f32 %0, %1, %2" : "=v"(r) : "v"(lo), "v"(hi));
  return r;
}
__device__ __forceinline__ float leaky(float f) {
  return fmaf(0.01f, fminf(f, 0.f), fmaxf(f, 0.f));
}

// Pad chunk-plane size (16B units) so staging writes / fragment reads spread
// across all 32 banks. KC=8 -> NCHP % 8 == 1 ; KC=4 -> NCHP % 8 == 2.
constexpr int pad_nch(int nch, int kc) {
  int res = (kc == 8) ? 1 : 2;
  while (nch % 8 != res) ++nch;
  return nch;
}

// ---------------------------------------------------------------------------
// Mask kernel: cnt = clamp(cin * boxsum3x3_dil(m), 1e-5), mnew = maxpool3x3_dil
// ---------------------------------------------------------------------------
__global__ void mask_kernel(const float* __restrict__ m, float* __restrict__ cnt,
                            float* __restrict__ mnew, int d, float cin) {
  int idx = blockIdx.x * 256 + threadIdx.x;
  int b = idx >> 16;
  int hw = idx & (HW_ - 1);
  int h = hw >> 8, w = hw & (W_ - 1);
  const float* mb = m + b * HW_;
  float s = 0.f, mx = 0.f;
#pragma unroll
  for (int kh = 0; kh < 3; ++kh) {
    int hh = h + (kh - 1) * d;
    if ((unsigned)hh >= (unsigned)H_) continue;
#pragma unroll
    for (int kw = 0; kw < 3; ++kw) {
      int ww = w + (kw - 1) * d;
      if ((unsigned)ww >= (unsigned)W_) continue;
      float v = mb[hh * W_ + ww];
      s += v;
      mx = fmaxf(mx, v);
    }
  }
  cnt[idx] = fmaxf(s * cin, 1e-5f);
  mnew[idx] = mx;
}

// ---------------------------------------------------------------------------
// Weight prepack into MFMA B-fragment order, bf16.
// ---------------------------------------------------------------------------
__global__ void pack_w(const float* __restrict__ Wsrc, short* __restrict__ pk,
                       int CINP, int CINR, int COUT, int S, int is1x1) {
  int idx = blockIdx.x * 256 + threadIdx.x;
  int NB = COUT >> 4;
  if (idx >= S * NB * 512) return;
  int j = idx & 7;
  int lane = (idx >> 3) & 63;
  int nb = (idx >> 9) % NB;
  int s = idx / (NB << 9);
  int k = s * 32 + ((lane >> 4) << 3) + j;
  int n = (nb << 4) + (lane & 15);
  float v = 0.f;
  if (is1x1) {
    if (k < CINR) v = Wsrc[n * CINR + k];
  } else if (k < 9 * CINP) {
    int t = k / CINP, ci = k % CINP;
    if (ci < CINR) v = Wsrc[(n * CINR + ci) * 9 + t];
  }
  pk[idx] = f2bf(v);
}

// ---------------------------------------------------------------------------
// prep0: feat NCHW fp32 * mask -> NHWC bf16 (32 channels)
// ---------------------------------------------------------------------------
__global__ void prep0(const float* __restrict__ feat, const float* __restrict__ m,
                      short* __restrict__ xm) {
  int pix = blockIdx.x * 256 + threadIdx.x;
  float mv = m[pix];
  int b = pix >> 16, hw = pix & (HW_ - 1);
  const float* fp = feat + (size_t)b * 32 * HW_ + hw;
  short8 ov[4];
#pragma unroll
  for (int k = 0; k < 4; ++k)
#pragma unroll
    for (int c = 0; c < 8; ++c)
      ov[k][c] = f2bf(fp[(size_t)(k * 8 + c) * HW_] * mv);
  short8* dst = (short8*)(xm + (size_t)pix * 32);
#pragma unroll
  for (int k = 0; k < 4; ++k) dst[k] = ov[k];
}

__global__ void bn_prep(float* __restrict__ st, const float* __restrict__ g,
                        const float* __restrict__ be, int C, float invN) {
  int c = threadIdx.x;
  if (c >= C) return;
  float mean = st[2 * c] * invN;
  float var = st[2 * c + 1] * invN - mean * mean;
  float a = g[c] * rsqrtf(var + 1e-5f);
  st[2 * c] = a;
  st[2 * c + 1] = be[c] - a * mean;
}

// ---------------------------------------------------------------------------
// LDS-staged MFMA implicit-GEMM 3x3 dilated conv with fused input BN and
// fused output BN-stats. NHWC bf16 in/out.
// Staging: batched global loads (4 in flight) -> BN+leaky (cvt_pk) -> ds_write.
// Mask multiply == packed select (mask is 0/1; also covers OOB zeroing).
// Epilogue: acc*rcp(cnt)+bias -> cvt_pk -> bf16 y; stats shfl-reduced over
// quads, then one LDS atomic per (wave,channel), one global atomic per block.
// ---------------------------------------------------------------------------
template <int CIN, int CINR, int COUT, int D, int MF, int NF, int NSPLIT,
          int TH, int TW, int FUSE>
__global__ __launch_bounds__(512, 4) void conv3_lds(
    const short* __restrict__ xin, const short* __restrict__ pk,
    const float* __restrict__ cnt, const float* __restrict__ bias,
    const float* __restrict__ stIn, const float* __restrict__ mask,
    float* __restrict__ stOut, short* __restrict__ y) {
  constexpr int KC = CIN / 8;          // staged 16B chunks per pixel (padded)
  constexpr int KCR = (CINR + 7) / 8;  // real chunks present in input
  constexpr int ICH = FUSE ? CINR : CIN;
  constexpr int CC = CIN / 32;
  constexpr int NB = COUT / 16;
  constexpr int RT = TH + 2 * D;
  constexpr int WT = TW + 2 * D;
  constexpr int NCH = RT * WT;
  constexpr int NCHP = pad_nch(NCH, KC);
  constexpr int NELEM = NCH * KC;
  constexpr int ROUNDS = (NELEM + 511) / 512;
  static_assert(TH * TW == (8 / NSPLIT) * MF * 16, "wave tiling mismatch");
  static_assert(NCHP * KC * 16 <= 62 * 1024, "LDS over budget");

  __shared__ short lds[NCHP * KC * 8];
  __shared__ float bins[2 * COUT];

  int tid = threadIdx.x;
  int lane = tid & 63;
  int wv = tid >> 6;
  int quad = lane >> 4, l16 = lane & 15;
  int b = blockIdx.z;
  int h0 = blockIdx.y * TH;
  int w0 = blockIdx.x * TW;

  for (int i = tid; i < 2 * COUT; i += 512) bins[i] = 0.f;

  // ---- stage A tile ----
  int cl = tid % KC;                    // chunk class, loop-invariant
  float av[8], bv[8];
  if (FUSE) {
#pragma unroll
    for (int k = 0; k < 8; ++k) {
      av[k] = stIn[2 * (cl * 8 + k)];
      bv[k] = stIn[2 * (cl * 8 + k) + 1];
    }
  }
  const short* xb = xin + (size_t)b * HW_ * ICH;
  const float* mb = mask + (size_t)b * HW_;
  int clc = cl < KCR ? cl : KCR - 1;

#pragma unroll
  for (int base = 0; base < ROUNDS; base += 4) {
    short8 raw[4];
    float mvv[4];
#pragma unroll
    for (int k = 0; k < 4; ++k) {
      int rd = base + k;
      if (rd >= ROUNDS) continue;
      int e = tid + rd * 512;
      int p = (e / KC) % WT;
      int r = e / (KC * WT);
      int gh = h0 + r - D, gw = w0 + p - D;
      bool inb = e < NELEM && (unsigned)gh < (unsigned)H_ &&
                 (unsigned)gw < (unsigned)W_ && cl < KCR;
      int ghc = gh < 0 ? 0 : (gh >= H_ ? H_ - 1 : gh);
      int gwc = gw < 0 ? 0 : (gw >= W_ ? W_ - 1 : gw);
      size_t off = ((size_t)ghc * W_ + gwc);
      raw[k] = *(const short8*)(xb + off * ICH + clc * 8);   // always in-bounds
      mvv[k] = inb ? (FUSE ? mb[off] : 1.f) : 0.f;
    }
#pragma unroll
    for (int k = 0; k < 4; ++k) {
      int rd = base + k;
      if (rd >= ROUNDS) continue;
      int e = tid + rd * 512;
      int p = (e / KC) % WT;
      int r = e / (KC * WT);
      union { short8 s; unsigned u[4]; } v;
      bool live = mvv[k] != 0.f;
      if (FUSE) {
#pragma unroll
        for (int q = 0; q < 4; ++q) {
          float f0 = leaky(fmaf(av[2 * q], bf2f(raw[k][2 * q]), bv[2 * q]));
          float f1 = leaky(fmaf(av[2 * q + 1], bf2f(raw[k][2 * q + 1]), bv[2 * q + 1]));
          unsigned u = cvt_pk_bf16(f0, f1);
          v.u[q] = live ? u : 0u;
        }
      } else {
        union { short8 s; unsigned u[4]; } rw; rw.s = raw[k];
#pragma unroll
        for (int q = 0; q < 4; ++q) v.u[q] = live ? rw.u[q] : 0u;
      }
      if (e < NELEM)
        *(short8*)(lds + ((size_t)cl * NCHP + r * WT + p) * 8) = v.s;
    }
  }
  __syncthreads();

  int nsec = wv % NSPLIT;
  int msec = wv / NSPLIT;
  int nb0 = nsec * NF;

  f32x4 acc[MF][NF];
#pragma unroll
  for (int i = 0; i < MF; ++i)
#pragma unroll
    for (int j = 0; j < NF; ++j) acc[i][j] = (f32x4){0.f, 0.f, 0.f, 0.f};

  const short* pkw = pk + (size_t)(nb0 * 64 + lane) * 8;

  int fb[MF];
#pragma unroll
  for (int i = 0; i < MF; ++i) {
    int flat = (msec * MF + i) * 16;
    fb[i] = (flat / TW) * WT + (flat % TW) + l16;
  }

#pragma unroll
  for (int t = 0; t < 9; ++t) {
    int toff = (t / 3) * D * WT + (t % 3) * D;
#pragma unroll
    for (int cc = 0; cc < CC; ++cc) {
      int s = t * CC + cc;
      int cbase = (cc * 4 + quad) * NCHP + toff;
      short8 a[MF], bb[NF];
#pragma unroll
      for (int i = 0; i < MF; ++i)
        a[i] = *(const short8*)(lds + (size_t)(cbase + fb[i]) * 8);
#pragma unroll
      for (int j = 0; j < NF; ++j)
        bb[j] = *(const short8*)(pkw + ((size_t)s * NB + j) * 512);
#pragma unroll
      for (int i = 0; i < MF; ++i)
#pragma unroll
        for (int j = 0; j < NF; ++j)
          acc[i][j] = __builtin_amdgcn_mfma_f32_16x16x32_bf16(a[i], bb[j], acc[i][j], 0, 0, 0);
    }
  }

  // ---- epilogue ----
  float sums[NF], sqs[NF];
#pragma unroll
  for (int j = 0; j < NF; ++j) { sums[j] = 0.f; sqs[j] = 0.f; }
#pragma unroll
  for (int i = 0; i < MF; ++i) {
    int flat = (msec * MF + i) * 16;
    int row_i = flat / TW, col_i = flat % TW;
    int hout = h0 + row_i;
    const size_t rowb = (size_t)(b * H_ + hout) * W_;
    int pw0 = w0 + col_i + quad * 4;
    float ic[4];
#pragma unroll
    for (int r = 0; r < 4; ++r)
      ic[r] = __builtin_amdgcn_rcpf(cnt[(size_t)b * HW_ + hout * W_ + pw0 + r]);
#pragma unroll
    for (int j = 0; j < NF; ++j) {
      int co = (nb0 + j) * 16 + l16;
      float v0 = fmaf(acc[i][j][0], ic[0], bias[co]);
      float v1 = fmaf(acc[i][j][1], ic[1], bias[co]);
      float v2 = fmaf(acc[i][j][2], ic[2], bias[co]);
      float v3 = fmaf(acc[i][j][3], ic[3], bias[co]);
      sums[j] += (v0 + v1) + (v2 + v3);
      sqs[j] += fmaf(v0, v0, fmaf(v1, v1, fmaf(v2, v2, v3 * v3)));
      unsigned u0 = cvt_pk_bf16(v0, v1);
      unsigned u1 = cvt_pk_bf16(v2, v3);
      short* yp = y + (rowb + pw0) * COUT + co;
      yp[0 * COUT] = (short)(u0 & 0xffff);
      yp[1 * COUT] = (short)(u0 >> 16);
      yp[2 * COUT] = (short)(u1 & 0xffff);
      yp[3 * COUT] = (short)(u1 >> 16);
    }
  }
  // quad shfl-reduce, then one LDS atomic per (wave, channel)
#pragma unroll
  for (int j = 0; j < NF; ++j) {
    sums[j] += __shfl_xor(sums[j], 16);
    sums[j] += __shfl_xor(sums[j], 32);
    sqs[j] += __shfl_xor(sqs[j], 16);
    sqs[j] += __shfl_xor(sqs[j], 32);
  }
  if (quad == 0) {
#pragma unroll
    for (int j = 0; j < NF; ++j) {
      int co = (nb0 + j) * 16 + l16;
      atomicAdd(&bins[2 * co], sums[j]);
      atomicAdd(&bins[2 * co + 1], sqs[j]);
    }
  }
  __syncthreads();
  for (int i = tid; i < 2 * COUT; i += 512) atomicAdd(&stOut[i], bins[i]);
}

// ---------------------------------------------------------------------------
// Final 1x1 conv with fused input BN+leaky: NHWC bf16 (128) -> NCHW fp32 (64).
// ---------------------------------------------------------------------------
__global__ __launch_bounds__(256) void conv1x1_mfma(
    const short* __restrict__ xf, const short* __restrict__ pk,
    const float* __restrict__ stIn, const float* __restrict__ bias,
    float* __restrict__ out) {
  constexpr int CIN = 128, NB = 4;
  int lane = threadIdx.x & 63, wv = threadIdx.x >> 6;
  int quad = lane >> 4, l16 = lane & 15;
  int w0 = blockIdx.x * 128, h = blockIdx.y, b = blockIdx.z;
  int mw0 = w0 + wv * 32;
  f32x4 acc[2][4];
#pragma unroll
  for (int i = 0; i < 2; ++i)
#pragma unroll
    for (int j = 0; j < 4; ++j) acc[i][j] = (f32x4){0.f, 0.f, 0.f, 0.f};
  const short* base0 = xf + ((size_t)(b * H_ + h) * W_ + mw0 + l16) * CIN + quad * 8;
  const short* pkw = pk + (size_t)lane * 8;
#pragma unroll
  for (int s = 0; s < 4; ++s) {
    float aa[8], bb2[8];
#pragma unroll
    for (int k = 0; k < 8; ++k) {
      int ch = s * 32 + quad * 8 + k;
      aa[k] = stIn[2 * ch];
      bb2[k] = stIn[2 * ch + 1];
    }
    short8 r0 = *(const short8*)(base0 + s * 32);
    short8 r1 = *(const short8*)(base0 + 16 * CIN + s * 32);
    union { short8 s; unsigned u[4]; } A0, A1;
#pragma unroll
    for (int q = 0; q < 4; ++q) {
      float f0 = leaky(fmaf(aa[2 * q], bf2f(r0[2 * q]), bb2[2 * q]));
      float f1 = leaky(fmaf(aa[2 * q + 1], bf2f(r0[2 * q + 1]), bb2[2 * q + 1]));
      A0.u[q] = cvt_pk_bf16(f0, f1);
      float g0 = leaky(fmaf(aa[2 * q], bf2f(r1[2 * q]), bb2[2 * q]));
      float g1 = leaky(fmaf(aa[2 * q + 1], bf2f(r1[2 * q + 1]), bb2[2 * q + 1]));
      A1.u[q] = cvt_pk_bf16(g0, g1);
    }
    short8 bb[4];
#pragma unroll
    for (int j = 0; j < 4; ++j) bb[j] = *(const short8*)(pkw + ((size_t)s * NB + j) * 512);
#pragma unroll
    for (int j = 0; j < 4; ++j) {
      acc[0][j] = __builtin_amdgcn_mfma_f32_16x16x32_bf16(A0.s, bb[j], acc[0][j], 0, 0, 0);
      acc[1][j] = __builtin_amdgcn_mfma_f32_16x16x32_bf16(A1.s, bb[j], acc[1][j], 0, 0, 0);
    }
  }
#pragma unroll
  for (int i = 0; i < 2; ++i)
#pragma unroll
    for (int r = 0; r < 4; ++r) {
      int pw = mw0 + i * 16 + quad * 4 + r;
#pragma unroll
      for (int j = 0; j < 4; ++j) {
        int co = j * 16 + l16;
        out[((size_t)b * 64 + co) * HW_ + h * W_ + pw] = acc[i][j][r] + bias[co];
      }
    }
}

__global__ void copy4_kernel(const float4* __restrict__ src, float4* __restrict__ dst) {
  int idx = blockIdx.x * 256 + threadIdx.x;
  dst[idx] = src[idx];
}

// ---------------------------------------------------------------------------
extern "C" void kernel_launch(void* const* d_in, const int* in_sizes, int n_in,
                              void* d_out, int out_size, void* d_ws, size_t ws_size,
                              hipStream_t stream) {
  const float* feat = (const float*)d_in[0];
  const float* mask = (const float*)d_in[1];
  const float *Wl[5], *bl[5], *gl[5], *bel[5];
  for (int l = 0; l < 5; ++l) {
    Wl[l]  = (const float*)d_in[2 + 4 * l];
    bl[l]  = (const float*)d_in[3 + 4 * l];
    gl[l]  = (const float*)d_in[4 + 4 * l];
    bel[l] = (const float*)d_in[5 + 4 * l];
  }
  const float* Wf = (const float*)d_in[22];
  const float* bf = (const float*)d_in[23];

  static const int COUTS[5] = {16, 32, 64, 64, 128};
  static const int CINP[5]  = {32, 32, 32, 64, 64};   // padded GEMM cin
  static const int CINR[5]  = {32, 16, 32, 64, 64};   // real weight cin
  static const int SST[5]   = {9, 9, 9, 18, 18};      // K-steps = 9*CINP/32

  // Workspace layout: two ping-pong NHWC activation buffers + masks + st + packs
  short* Ya = (short*)d_ws;                        // NPIX*128 bf16
  short* Yb = Ya + (size_t)NPIX * 128;             // NPIX*128 bf16
  float* mA = (float*)(Yb + (size_t)NPIX * 128);
  float* mB = mA + NPIX;
  float* cb = mB + NPIX;
  float* st = cb + NPIX;                           // 5 * 256 floats
  short* pkL[6];
  {
    short* p = (short*)(st + 5 * 256);
    for (int l = 0; l < 5; ++l) { pkL[l] = p; p += SST[l] * (COUTS[l] >> 4) * 512; }
    pkL[5] = p;                                    // 1x1: 4*4*512
  }

  hipMemsetAsync(st, 0, 5 * 256 * sizeof(float), stream);
  for (int l = 0; l < 5; ++l) {
    int sz = SST[l] * (COUTS[l] >> 4) * 512;
    pack_w<<<sz / 256, 256, 0, stream>>>(Wl[l], pkL[l], CINP[l], CINR[l], COUTS[l], SST[l], 0);
  }
  pack_w<<<4 * 4 * 512 / 256, 256, 0, stream>>>(Wf, pkL[5], 128, 128, 64, 4, 1);

  prep0<<<NPIX / 256, 256, 0, stream>>>(feat, mask, Ya);

  const float* mcur = mask;
  // buffers ping-pong: conv l reads bufs[l&1], writes bufs[(l+1)&1]
  short* bufs[2] = {Ya, Yb};

  for (int l = 0; l < 5; ++l) {
    float* mnext = (l & 1) ? mB : mA;
    mask_kernel<<<NPIX / 256, 256, 0, stream>>>(mcur, cb, mnext, (l == 1 || l == 3) ? 2 : 1,
                                                (float)CINR[l]);
    const short* xin = bufs[l & 1];
    short* yout = bufs[(l + 1) & 1];
    const float* stP = (l > 0) ? st + (l - 1) * 256 : st;  // unused for l==0
    float* stO = st + l * 256;

    switch (l) {
      case 0: conv3_lds<32, 32, 16, 1, 4, 1, 1, 8, 64, 0>
                <<<dim3(4, 32, 8), 512, 0, stream>>>(xin, pkL[0], cb, bl[0], stP, mcur, stO, yout); break;
      case 1: conv3_lds<32, 16, 32, 2, 4, 2, 1, 8, 64, 1>
                <<<dim3(4, 32, 8), 512, 0, stream>>>(xin, pkL[1], cb, bl[1], stP, mcur, stO, yout); break;
      case 2: conv3_lds<32, 32, 64, 1, 4, 4, 1, 8, 64, 1>
                <<<dim3(4, 32, 8), 512, 0, stream>>>(xin, pkL[2], cb, bl[2], stP, mcur, stO, yout); break;
      case 3: conv3_lds<64, 64, 64, 2, 4, 2, 2, 8, 32, 1>
                <<<dim3(8, 32, 8), 512, 0, stream>>>(xin, pkL[3], cb, bl[3], stP, mcur, stO, yout); break;
      case 4: conv3_lds<64, 64, 128, 1, 4, 4, 2, 4, 64, 1>
                <<<dim3(4, 64, 8), 512, 0, stream>>>(xin, pkL[4], cb, bl[4], stP, mcur, stO, yout); break;
    }

    bn_prep<<<1, 128, 0, stream>>>(stO, gl[l], bel[l], COUTS[l], 1.f / (float)NPIX);
    mcur = mnext;
  }

  conv1x1_mfma<<<dim3(2, 256, 8), 256, 0, stream>>>(bufs[1], pkL[5], st + 4 * 256, bf,
                                                    (float*)d_out);
  copy4_kernel<<<NPIX / 4 / 256, 256, 0, stream>>>(
      (const float4*)mcur, (float4*)d_out + ((size_t)B_ * 64 * HW_) / 4);
}